// Round 5
// baseline (2299.717 us; speedup 1.0000x reference)
//
#include <hip/hip_runtime.h>
#include <hip/hip_cooperative_groups.h>
#include <math.h>

namespace cg = cooperative_groups;

typedef short bf16x8 __attribute__((ext_vector_type(8)));
typedef float f32x4 __attribute__((ext_vector_type(4)));
typedef unsigned long long ull;
typedef unsigned int uint;
typedef unsigned short ushort;

#define Bz 32
#define Tz 50
#define Sz 40
#define Vz 32000
#define Dz 512
#define Hz 1024
#define Mz 1600
#define Mp 1664

__device__ __forceinline__ float bf2f(ushort h) {
    uint u = ((uint)h) << 16;
    return __builtin_bit_cast(float, u);
}
// truncation split: f = hi + rem
__device__ __forceinline__ void splitf(float f, ushort& hi, ushort& lo) {
    uint u = __builtin_bit_cast(uint, f);
    hi = (ushort)(u >> 16);
    float rem = f - __builtin_bit_cast(float, u & 0xFFFF0000u);
    lo = (ushort)(__builtin_bit_cast(uint, rem) >> 16);
}
__device__ __forceinline__ float sigf(float x) { return 1.f / (1.f + expf(-x)); }

// ---------- k_pre: init hxA[0] hi/lo, cx; zero AH pad rows ----------
__global__ __launch_bounds__(256) void k_pre(ushort* hxA_hi, ushort* hxA_lo, float* cx,
                                             ushort* AH_hi, ushort* AH_lo,
                                             const float* h0, const float* c0) {
    int gid = blockIdx.x * 256 + threadIdx.x;
    if (gid < 32768) {
        float v = h0[gid];
        ushort hi, lo;
        splitf(v, hi, lo);
        hxA_hi[gid] = hi;
        hxA_lo[gid] = lo;
    } else if (gid < 65536) {
        cx[gid - 32768] = c0[gid - 32768];
    } else {
        int g = gid - 65536;               // AH pad rows 1600..1663
        AH_hi[(long)Mz * 2048 + g] = 0;
        AH_lo[(long)Mz * 2048 + g] = 0;
    }
}

// ---------- k_wsplit: fp32 matrix -> bf16 hi/lo planes ----------
__global__ __launch_bounds__(256) void k_wsplit(const float* __restrict__ src,
                                                ushort* __restrict__ hi, ushort* __restrict__ lo,
                                                int n4) {
    int stride = gridDim.x * 256;
    for (int i = blockIdx.x * 256 + threadIdx.x; i < n4; i += stride) {
        float4 f = *(const float4*)(src + (long)i * 4);
        float vv[4] = {f.x, f.y, f.z, f.w};
        ushort h[4], l[4];
#pragma unroll
        for (int e = 0; e < 4; ++e) splitf(vv[e], h[e], l[e]);
        uint2 hp, lp;
        hp.x = (uint)h[0] | ((uint)h[1] << 16);
        hp.y = (uint)h[2] | ((uint)h[3] << 16);
        lp.x = (uint)l[0] | ((uint)l[1] << 16);
        lp.y = (uint)l[2] | ((uint)l[3] << 16);
        *(uint2*)(hi + (long)i * 4) = hp;
        *(uint2*)(lo + (long)i * 4) = lp;
    }
}

// ---------- k_xgemm: gates_x = emb[tok] @ Wih^T + bih + bhh (split-bf16 MFMA) ----------
__global__ __launch_bounds__(256, 1) void k_xgemm(const float* __restrict__ emb,
                                                  const int* __restrict__ tok,
                                                  const float* __restrict__ Wih,
                                                  const float* __restrict__ bih,
                                                  const float* __restrict__ bhh,
                                                  float* __restrict__ gx) {
    __shared__ ushort sAh[128][40];
    __shared__ ushort sAl[128][40];
    __shared__ ushort sBh[128][40];
    __shared__ ushort sBl[128][40];
    int bid = blockIdx.x;
    int mt = bid >> 5, nt = bid & 31;
    int tid = threadIdx.x;
    int row = tid >> 1, half = tid & 1;
    int wv = tid >> 6, lane = tid & 63;
    int wr = wv >> 1, wc = wv & 1;
    int m0 = wr * 64, n0 = wc * 64;
    int r16 = lane & 15, kg = lane >> 4, k0 = kg * 8;

    f32x4 acc[4][4];
#pragma unroll
    for (int i = 0; i < 4; i++)
#pragma unroll
        for (int j = 0; j < 4; j++) acc[i][j] = (f32x4){0.f, 0.f, 0.f, 0.f};

    int r = mt * 128 + row;
    int tk = (r < Mz) ? tok[r] : 0;
    const float* arow = emb + (long)tk * Dz;
    const float* brow = Wih + (long)(nt * 128 + row) * Dz;

    for (int kb = 0; kb < Dz; kb += 32) {
        {
            ushort hh[16], ll[16];
#pragma unroll
            for (int q = 0; q < 16; q += 4) {
                float4 w4 = (r < Mz) ? *(const float4*)(arow + kb + half * 16 + q)
                                     : (float4){0.f, 0.f, 0.f, 0.f};
                float vv[4] = {w4.x, w4.y, w4.z, w4.w};
#pragma unroll
                for (int e = 0; e < 4; ++e) splitf(vv[e], hh[q + e], ll[q + e]);
            }
            *(uint4*)&sAh[row][half * 16]     = *(uint4*)&hh[0];
            *(uint4*)&sAh[row][half * 16 + 8] = *(uint4*)&hh[8];
            *(uint4*)&sAl[row][half * 16]     = *(uint4*)&ll[0];
            *(uint4*)&sAl[row][half * 16 + 8] = *(uint4*)&ll[8];
        }
        {
            ushort hh[16], ll[16];
#pragma unroll
            for (int q = 0; q < 16; q += 4) {
                float4 w4 = *(const float4*)(brow + kb + half * 16 + q);
                float vv[4] = {w4.x, w4.y, w4.z, w4.w};
#pragma unroll
                for (int e = 0; e < 4; ++e) splitf(vv[e], hh[q + e], ll[q + e]);
            }
            *(uint4*)&sBh[row][half * 16]     = *(uint4*)&hh[0];
            *(uint4*)&sBh[row][half * 16 + 8] = *(uint4*)&hh[8];
            *(uint4*)&sBl[row][half * 16]     = *(uint4*)&ll[0];
            *(uint4*)&sBl[row][half * 16 + 8] = *(uint4*)&ll[8];
        }
        __syncthreads();
        bf16x8 af[4], alf[4], bhf[4], blf[4];
#pragma unroll
        for (int i = 0; i < 4; ++i) {
            af[i]  = *(const bf16x8*)&sAh[m0 + i * 16 + r16][k0];
            alf[i] = *(const bf16x8*)&sAl[m0 + i * 16 + r16][k0];
            bhf[i] = *(const bf16x8*)&sBh[n0 + i * 16 + r16][k0];
            blf[i] = *(const bf16x8*)&sBl[n0 + i * 16 + r16][k0];
        }
#pragma unroll
        for (int i = 0; i < 4; ++i)
#pragma unroll
            for (int jn = 0; jn < 4; ++jn) {
                acc[i][jn] = __builtin_amdgcn_mfma_f32_16x16x32_bf16(af[i],  bhf[jn], acc[i][jn], 0, 0, 0);
                acc[i][jn] = __builtin_amdgcn_mfma_f32_16x16x32_bf16(af[i],  blf[jn], acc[i][jn], 0, 0, 0);
                acc[i][jn] = __builtin_amdgcn_mfma_f32_16x16x32_bf16(alf[i], bhf[jn], acc[i][jn], 0, 0, 0);
            }
        __syncthreads();
    }
#pragma unroll
    for (int i = 0; i < 4; ++i) {
        int gr0 = mt * 128 + m0 + i * 16 + kg * 4;
#pragma unroll
        for (int reg = 0; reg < 4; ++reg) {
            int gr = gr0 + reg;
            if (gr >= Mz) continue;
#pragma unroll
            for (int jn = 0; jn < 4; ++jn) {
                int gc = nt * 128 + n0 + jn * 16 + r16;
                gx[(long)gr * 4096 + gc] = acc[i][jn][reg] + bih[gc] + bhh[gc];
            }
        }
    }
}

// ---------- k_recfused: all 50 LSTM steps + per-step attention, ONE cooperative launch ----------
// WGs 0..63: gates MFMA + cell for step t.  WGs 64..95: attention for step t-1 (b = wid-64).
__global__ __launch_bounds__(512, 1) void k_recfused(
    const float* __restrict__ gx,
    const ushort* __restrict__ Whi, const ushort* __restrict__ Wlo,
    ushort* __restrict__ hxA_hi, ushort* __restrict__ hxA_lo,
    float* __restrict__ hxh, float* __restrict__ cx,
    const float* __restrict__ enc,
    ushort* __restrict__ AH_hi, ushort* __restrict__ AH_lo) {
    cg::grid_group grid = cg::this_grid();
    __shared__ float sg[2][4][32][16];
    __shared__ float hxs[Hz];
    __shared__ float sc[64];
    __shared__ float aw[Sz];
    int wid = blockIdx.x, tid = threadIdx.x;

    for (int t = 0; t <= Tz; ++t) {
        if (wid < 64) {
            if (t < Tz) {
                int w = wid;
                int wave = tid >> 6, lane = tid & 63;
                int v = wave & 3, kh = wave >> 2;
                int r16 = lane & 15, kg = lane >> 4;
                int p = t & 1, q = p ^ 1;
                const ushort* Ah = hxA_hi + p * 32768;
                const ushort* Al = hxA_lo + p * 32768;
                int j = v * 1024 + w * 16 + r16;
                const ushort* bhp = Whi + (long)j * 1024;
                const ushort* blp = Wlo + (long)j * 1024;
                f32x4 acc0 = {0.f, 0.f, 0.f, 0.f}, acc1 = {0.f, 0.f, 0.f, 0.f};
                int kbase = kh * 512 + kg * 8;
#pragma unroll 4
                for (int it = 0; it < 16; ++it) {
                    int k0 = kbase + it * 32;
                    bf16x8 a_h0 = *(const bf16x8*)(Ah + r16 * 1024 + k0);
                    bf16x8 a_l0 = *(const bf16x8*)(Al + r16 * 1024 + k0);
                    bf16x8 a_h1 = *(const bf16x8*)(Ah + (16 + r16) * 1024 + k0);
                    bf16x8 a_l1 = *(const bf16x8*)(Al + (16 + r16) * 1024 + k0);
                    bf16x8 b_h = *(const bf16x8*)(bhp + k0);
                    bf16x8 b_l = *(const bf16x8*)(blp + k0);
                    acc0 = __builtin_amdgcn_mfma_f32_16x16x32_bf16(a_h0, b_h, acc0, 0, 0, 0);
                    acc0 = __builtin_amdgcn_mfma_f32_16x16x32_bf16(a_l0, b_h, acc0, 0, 0, 0);
                    acc0 = __builtin_amdgcn_mfma_f32_16x16x32_bf16(a_h0, b_l, acc0, 0, 0, 0);
                    acc1 = __builtin_amdgcn_mfma_f32_16x16x32_bf16(a_h1, b_h, acc1, 0, 0, 0);
                    acc1 = __builtin_amdgcn_mfma_f32_16x16x32_bf16(a_l1, b_h, acc1, 0, 0, 0);
                    acc1 = __builtin_amdgcn_mfma_f32_16x16x32_bf16(a_h1, b_l, acc1, 0, 0, 0);
                }
#pragma unroll
                for (int reg = 0; reg < 4; ++reg) {
                    sg[kh][v][kg * 4 + reg][r16]      = acc0[reg];
                    sg[kh][v][16 + kg * 4 + reg][r16] = acc1[reg];
                }
                __syncthreads();
                int b = tid >> 4, h16 = tid & 15;
                int hg = w * 16 + h16;
                const float* gxr = gx + ((long)b * Tz + t) * 4096 + hg;
                float gi = sg[0][0][b][h16] + sg[1][0][b][h16] + gxr[0];
                float gf = sg[0][1][b][h16] + sg[1][1][b][h16] + gxr[1024];
                float gg = sg[0][2][b][h16] + sg[1][2][b][h16] + gxr[2048];
                float go = sg[0][3][b][h16] + sg[1][3][b][h16] + gxr[3072];
                long ci = (long)b * Hz + hg;
                float c = sigf(gf) * cx[ci] + sigf(gi) * tanhf(gg);
                float hv = sigf(go) * tanhf(c);
                cx[ci] = c;
                hxh[((long)t * Bz + b) * Hz + hg] = hv;
                ushort hi, lo;
                splitf(hv, hi, lo);
                hxA_hi[q * 32768 + ci] = hi;
                hxA_lo[q * 32768 + ci] = lo;
            }
        } else {
            if (t > 0) {
                int b = wid - 64, tt = t - 1;
                const float* hsrc = hxh + ((long)tt * Bz + b) * Hz;
                *(float2*)&hxs[tid * 2] = *(const float2*)(hsrc + tid * 2);
                __syncthreads();
                int wv = tid >> 6, lane = tid & 63;
                float hreg[16];
#pragma unroll
                for (int u = 0; u < 16; ++u) hreg[u] = hxs[lane * 16 + u];
                const float* eb = enc + (long)b * Sz * Hz;
                for (int s = wv; s < Sz; s += 8) {
                    const float* er = eb + (long)s * Hz + lane * 16;
                    float sum = 0.f;
#pragma unroll
                    for (int qq = 0; qq < 4; ++qq) {
                        float4 e4 = *(const float4*)(er + qq * 4);
                        sum += e4.x * hreg[qq*4] + e4.y * hreg[qq*4+1] + e4.z * hreg[qq*4+2] + e4.w * hreg[qq*4+3];
                    }
#pragma unroll
                    for (int off = 32; off >= 1; off >>= 1) sum += __shfl_xor(sum, off);
                    if (lane == 0) sc[s] = sum;
                }
                __syncthreads();
                if (tid < 64) {
                    float vv = (tid < Sz) ? sc[tid] : -3.402823e38f;
                    float mx = vv;
#pragma unroll
                    for (int off = 32; off >= 1; off >>= 1) mx = fmaxf(mx, __shfl_xor(mx, off));
                    float e = (tid < Sz) ? expf(vv - mx) : 0.f;
                    float ssum = e;
#pragma unroll
                    for (int off = 32; off >= 1; off >>= 1) ssum += __shfl_xor(ssum, off);
                    if (tid < Sz) aw[tid] = e / ssum;
                }
                __syncthreads();
                float c0 = 0.f, c1 = 0.f;
#pragma unroll 4
                for (int s = 0; s < Sz; ++s) {
                    float2 e2 = *(const float2*)(eb + (long)s * Hz + tid * 2);
                    float a = aw[s];
                    c0 += a * e2.x; c1 += a * e2.y;
                }
                long rr = (long)b * Tz + tt;
                ushort* dh = AH_hi + rr * 2048;
                ushort* dl = AH_lo + rr * 2048;
                ushort hi, lo;
                splitf(c0, hi, lo); dh[tid * 2]        = hi; dl[tid * 2]        = lo;
                splitf(c1, hi, lo); dh[tid * 2 + 1]    = hi; dl[tid * 2 + 1]    = lo;
                splitf(hxs[tid * 2],     hi, lo); dh[1024 + tid * 2]     = hi; dl[1024 + tid * 2]     = lo;
                splitf(hxs[tid * 2 + 1], hi, lo); dh[1024 + tid * 2 + 1] = hi; dl[1024 + tid * 2 + 1] = lo;
            }
        }
        grid.sync();
    }
}

// ---------- k_ht: HXA = tanh(AH @ Wht^T + bht) -> bf16 hi/lo (pre-split B) ----------
__global__ __launch_bounds__(256, 1) void k_ht(const ushort* __restrict__ Ah,
                                               const ushort* __restrict__ Al,
                                               const ushort* __restrict__ Bh,
                                               const ushort* __restrict__ Bl,
                                               const float* __restrict__ bht,
                                               ushort* __restrict__ Hh, ushort* __restrict__ Hl) {
    __shared__ ushort sAh[128][40];
    __shared__ ushort sAl[128][40];
    __shared__ ushort sBh[128][40];
    __shared__ ushort sBl[128][40];
    int bid = blockIdx.x;
    int mt = bid >> 3, nt = bid & 7;
    int tid = threadIdx.x;
    int row = tid >> 1, half = tid & 1;
    int wv = tid >> 6, lane = tid & 63;
    int wr = wv >> 1, wc = wv & 1;
    int m0 = wr * 64, n0 = wc * 64;
    int r16 = lane & 15, kg = lane >> 4, k0 = kg * 8;

    f32x4 acc[4][4];
#pragma unroll
    for (int i = 0; i < 4; i++)
#pragma unroll
        for (int j = 0; j < 4; j++) acc[i][j] = (f32x4){0.f, 0.f, 0.f, 0.f};

    long arow = (long)(mt * 128 + row) * 2048;
    long brow = (long)(nt * 128 + row) * 2048;

    for (int kb = 0; kb < 2048; kb += 32) {
        const ushort* pa = Ah + arow + kb + half * 16;
        *(uint4*)&sAh[row][half * 16]     = *(const uint4*)pa;
        *(uint4*)&sAh[row][half * 16 + 8] = *(const uint4*)(pa + 8);
        const ushort* pl = Al + arow + kb + half * 16;
        *(uint4*)&sAl[row][half * 16]     = *(const uint4*)pl;
        *(uint4*)&sAl[row][half * 16 + 8] = *(const uint4*)(pl + 8);
        const ushort* pb = Bh + brow + kb + half * 16;
        *(uint4*)&sBh[row][half * 16]     = *(const uint4*)pb;
        *(uint4*)&sBh[row][half * 16 + 8] = *(const uint4*)(pb + 8);
        const ushort* pc = Bl + brow + kb + half * 16;
        *(uint4*)&sBl[row][half * 16]     = *(const uint4*)pc;
        *(uint4*)&sBl[row][half * 16 + 8] = *(const uint4*)(pc + 8);
        __syncthreads();
        bf16x8 af[4], alf[4], bhf[4], blf[4];
#pragma unroll
        for (int i = 0; i < 4; ++i) {
            af[i]  = *(const bf16x8*)&sAh[m0 + i * 16 + r16][k0];
            alf[i] = *(const bf16x8*)&sAl[m0 + i * 16 + r16][k0];
            bhf[i] = *(const bf16x8*)&sBh[n0 + i * 16 + r16][k0];
            blf[i] = *(const bf16x8*)&sBl[n0 + i * 16 + r16][k0];
        }
#pragma unroll
        for (int i = 0; i < 4; ++i)
#pragma unroll
            for (int jn = 0; jn < 4; ++jn) {
                acc[i][jn] = __builtin_amdgcn_mfma_f32_16x16x32_bf16(af[i],  bhf[jn], acc[i][jn], 0, 0, 0);
                acc[i][jn] = __builtin_amdgcn_mfma_f32_16x16x32_bf16(af[i],  blf[jn], acc[i][jn], 0, 0, 0);
                acc[i][jn] = __builtin_amdgcn_mfma_f32_16x16x32_bf16(alf[i], bhf[jn], acc[i][jn], 0, 0, 0);
            }
        __syncthreads();
    }
#pragma unroll
    for (int i = 0; i < 4; ++i) {
        int gr0 = mt * 128 + m0 + i * 16 + kg * 4;
#pragma unroll
        for (int reg = 0; reg < 4; ++reg) {
            int gr = gr0 + reg;
            bool valid = gr < Mz;
#pragma unroll
            for (int jn = 0; jn < 4; ++jn) {
                int gc = nt * 128 + n0 + jn * 16 + r16;
                float vv = tanhf(acc[i][jn][reg] + bht[gc]);
                ushort hi = 0, lo = 0;
                if (valid) splitf(vv, hi, lo);
                Hh[(long)gr * Hz + gc] = hi;
                Hl[(long)gr * Hz + gc] = lo;
            }
        }
    }
}

// ---------- k_voc3: n-panel-persistent logits GEMM (pre-split planes) + fused argmax keys ----------
__global__ __launch_bounds__(256, 1) void k_voc3(
    const ushort* __restrict__ Ah, const ushort* __restrict__ Al,
    const ushort* __restrict__ Wh, const ushort* __restrict__ Wl,
    const float* __restrict__ bvoc,
    float* __restrict__ out, ull* __restrict__ keys) {
    __shared__ ushort sAh[128][40];
    __shared__ ushort sAl[128][40];
    __shared__ ushort sBh[128][40];
    __shared__ ushort sBl[128][40];
    int bid = blockIdx.x;
    int nt = bid % 250, mg = bid / 250;       // mg in {0,1}
    int mt_beg = (mg == 0) ? 0 : 7;
    int mt_end = (mg == 0) ? 7 : 13;
    int tid = threadIdx.x;
    int row = tid >> 1, half = tid & 1;
    int wv = tid >> 6, lane = tid & 63;
    int wr = wv >> 1, wc = wv & 1;
    int m0 = wr * 64, n0 = wc * 64;
    int r16 = lane & 15, kg = lane >> 4, k0 = kg * 8;

    long wrow = (long)(nt * 128 + row) * Hz;
    int vcol_base = nt * 128 + n0;

    for (int mt = mt_beg; mt < mt_end; ++mt) {
        f32x4 acc[4][4];
#pragma unroll
        for (int i = 0; i < 4; i++)
#pragma unroll
            for (int j = 0; j < 4; j++) acc[i][j] = (f32x4){0.f, 0.f, 0.f, 0.f};

        long arow = (long)(mt * 128 + row) * Hz;

        for (int kb = 0; kb < Hz; kb += 32) {
            const ushort* pa = Ah + arow + kb + half * 16;
            *(uint4*)&sAh[row][half * 16]     = *(const uint4*)pa;
            *(uint4*)&sAh[row][half * 16 + 8] = *(const uint4*)(pa + 8);
            const ushort* pl = Al + arow + kb + half * 16;
            *(uint4*)&sAl[row][half * 16]     = *(const uint4*)pl;
            *(uint4*)&sAl[row][half * 16 + 8] = *(const uint4*)(pl + 8);
            const ushort* pb = Wh + wrow + kb + half * 16;
            *(uint4*)&sBh[row][half * 16]     = *(const uint4*)pb;
            *(uint4*)&sBh[row][half * 16 + 8] = *(const uint4*)(pb + 8);
            const ushort* pc = Wl + wrow + kb + half * 16;
            *(uint4*)&sBl[row][half * 16]     = *(const uint4*)pc;
            *(uint4*)&sBl[row][half * 16 + 8] = *(const uint4*)(pc + 8);
            __syncthreads();
            bf16x8 af[4], alf[4], bhf[4], blf[4];
#pragma unroll
            for (int i = 0; i < 4; ++i) {
                af[i]  = *(const bf16x8*)&sAh[m0 + i * 16 + r16][k0];
                alf[i] = *(const bf16x8*)&sAl[m0 + i * 16 + r16][k0];
                bhf[i] = *(const bf16x8*)&sBh[n0 + i * 16 + r16][k0];
                blf[i] = *(const bf16x8*)&sBl[n0 + i * 16 + r16][k0];
            }
#pragma unroll
            for (int i = 0; i < 4; ++i)
#pragma unroll
                for (int jn = 0; jn < 4; ++jn) {
                    acc[i][jn] = __builtin_amdgcn_mfma_f32_16x16x32_bf16(af[i],  bhf[jn], acc[i][jn], 0, 0, 0);
                    acc[i][jn] = __builtin_amdgcn_mfma_f32_16x16x32_bf16(af[i],  blf[jn], acc[i][jn], 0, 0, 0);
                    acc[i][jn] = __builtin_amdgcn_mfma_f32_16x16x32_bf16(alf[i], bhf[jn], acc[i][jn], 0, 0, 0);
                }
            __syncthreads();
        }
#pragma unroll
        for (int i = 0; i < 4; ++i) {
            int gr0 = mt * 128 + m0 + i * 16 + kg * 4;
#pragma unroll
            for (int reg = 0; reg < 4; ++reg) {
                int gr = gr0 + reg;
                bool valid = gr < Mz;
                float bestv = -3.402823e38f;
                int bestc = 0;
#pragma unroll
                for (int jn = 0; jn < 4; ++jn) {
                    int gc = vcol_base + jn * 16 + r16;
                    float v = acc[i][jn][reg] + bvoc[gc];
                    if (valid) __builtin_nontemporal_store(v, &out[(long)gr * Vz + gc]);
                    if (v > bestv) { bestv = v; bestc = gc; }
                }
#pragma unroll
                for (int off = 1; off < 16; off <<= 1) {
                    float ov = __shfl_xor(bestv, off);
                    int oc = __shfl_xor(bestc, off);
                    if (ov > bestv || (ov == bestv && oc < bestc)) { bestv = ov; bestc = oc; }
                }
                if (valid && r16 == 0) {
                    uint u = __builtin_bit_cast(uint, bestv);
                    u = (u & 0x80000000u) ? ~u : (u | 0x80000000u);
                    keys[(long)gr * 512 + nt * 2 + wc] = (((ull)u) << 32) | (ull)(65535 - bestc);
                }
            }
        }
    }
}

__global__ __launch_bounds__(256) void k_argmax2(const ull* __restrict__ keys, float* __restrict__ pred) {
    int r = blockIdx.x, tid = threadIdx.x;
    ull best = 0;
    for (int j = tid; j < 500; j += 256) {
        ull k = keys[(long)r * 512 + j];
        if (k > best) best = k;
    }
    __shared__ ull sk[256];
    sk[tid] = best;
    __syncthreads();
    for (int s = 128; s > 0; s >>= 1) {
        if (tid < s) { if (sk[tid + s] > sk[tid]) sk[tid] = sk[tid + s]; }
        __syncthreads();
    }
    if (tid == 0) pred[r] = (float)(65535 - (int)(sk[0] & 0xFFFFull));
}

// ---------------- host ----------------
extern "C" void kernel_launch(void* const* d_in, const int* in_sizes, int n_in,
                              void* d_out, int out_size, void* d_ws, size_t ws_size,
                              hipStream_t stream) {
    const int*   tok  = (const int*)d_in[0];
    const float* enc  = (const float*)d_in[1];
    const float* h0   = (const float*)d_in[2];
    const float* c0   = (const float*)d_in[3];
    const float* emb  = (const float*)d_in[6];
    const float* Wih  = (const float*)d_in[7];
    const float* Whh  = (const float*)d_in[8];
    const float* bih  = (const float*)d_in[9];
    const float* bhh  = (const float*)d_in[10];
    const float* Wht  = (const float*)d_in[11];
    const float* bht  = (const float*)d_in[12];
    const float* Wvoc = (const float*)d_in[13];
    const float* bvoc = (const float*)d_in[14];
    float* out = (float*)d_out;

    char* base = (char*)d_ws;
    // --- recurrence-phase region [0, 131MB): dead before k_voc3; overwritten by Wvoc planes ---
    size_t off = 0;
    float*  gx      = (float*)(base + off);  off += (size_t)Mz * 4096 * 4;       // 26.2 MB
    ushort* hxA_hi  = (ushort*)(base + off); off += 2 * 32768 * 2;
    ushort* hxA_lo  = (ushort*)(base + off); off += 2 * 32768 * 2;
    float*  cx      = (float*)(base + off);  off += 32768 * 4;
    float*  hxh     = (float*)(base + off);  off += (size_t)Tz * Bz * Hz * 4;    // 6.55 MB
    ushort* AH_hi   = (ushort*)(base + off); off += (size_t)Mp * 2048 * 2;       // 6.8 MB
    ushort* AH_lo   = (ushort*)(base + off); off += (size_t)Mp * 2048 * 2;
    ushort* Whh_hi  = (ushort*)(base + off); off += (size_t)4096 * 1024 * 2;
    ushort* Whh_lo  = (ushort*)(base + off); off += (size_t)4096 * 1024 * 2;
    ushort* Wht_hi  = (ushort*)(base + off); off += (size_t)1024 * 2048 * 2;
    ushort* Wht_lo  = (ushort*)(base + off); off += (size_t)1024 * 2048 * 2;     // ~72 MB total
    // aliased Wvoc planes (written after k_ht, when the region above is dead)
    ushort* Wvoc_hi = (ushort*)base;                                             // 65.5 MB
    ushort* Wvoc_lo = Wvoc_hi + (size_t)Vz * Hz;                                 // 65.5 MB (ends 131 MB)
    // --- survivors past 131 MB ---
    size_t off2 = (size_t)Vz * Hz * 2 * 2;                                       // 131,072,000
    ushort* HXA_hi  = (ushort*)(base + off2); off2 += (size_t)Mp * 1024 * 2;
    ushort* HXA_lo  = (ushort*)(base + off2); off2 += (size_t)Mp * 1024 * 2;
    ull*    keys    = (ull*)(base + off2);    off2 += (size_t)Mz * 512 * 8;      // ends ~144.4 MB

    k_pre<<<768, 256, 0, stream>>>(hxA_hi, hxA_lo, cx, AH_hi, AH_lo, h0, c0);
    k_wsplit<<<1024, 256, 0, stream>>>(Whh, Whh_hi, Whh_lo, 4096 * 1024 / 4);
    k_wsplit<<<512, 256, 0, stream>>>(Wht, Wht_hi, Wht_lo, 1024 * 2048 / 4);
    k_xgemm<<<13 * 32, 256, 0, stream>>>(emb, tok, Wih, bih, bhh, gx);

    void* args[] = { &gx, &Whh_hi, &Whh_lo, &hxA_hi, &hxA_lo, &hxh, &cx,
                     (void*)&enc, &AH_hi, &AH_lo };
    hipLaunchCooperativeKernel((const void*)k_recfused, dim3(96), dim3(512), args, 0, stream);

    k_ht<<<13 * 8, 256, 0, stream>>>(AH_hi, AH_lo, Wht_hi, Wht_lo, bht, HXA_hi, HXA_lo);
    k_wsplit<<<2048, 256, 0, stream>>>(Wvoc, Wvoc_hi, Wvoc_lo, Vz * Hz / 4);
    k_voc3<<<500, 256, 0, stream>>>(HXA_hi, HXA_lo, Wvoc_hi, Wvoc_lo, bvoc, out, keys);
    k_argmax2<<<Mz, 256, 0, stream>>>(keys, out + (long)Mz * Vz);
}

// Round 6
// 1954.268 us; speedup vs baseline: 1.1768x; 1.1768x over previous
//
#include <hip/hip_runtime.h>
#include <math.h>

typedef short bf16x8 __attribute__((ext_vector_type(8)));
typedef float f32x4 __attribute__((ext_vector_type(4)));
typedef unsigned long long ull;
typedef unsigned int uint;
typedef unsigned short ushort;

#define Bz 32
#define Tz 50
#define Sz 40
#define Vz 32000
#define Dz 512
#define Hz 1024
#define Mz 1600
#define Mp 1664
#define NWG_REC 96

__device__ __forceinline__ float bf2f(ushort h) {
    uint u = ((uint)h) << 16;
    return __builtin_bit_cast(float, u);
}
// truncation split: f = hi + rem
__device__ __forceinline__ void splitf(float f, ushort& hi, ushort& lo) {
    uint u = __builtin_bit_cast(uint, f);
    hi = (ushort)(u >> 16);
    float rem = f - __builtin_bit_cast(float, u & 0xFFFF0000u);
    lo = (ushort)(__builtin_bit_cast(uint, rem) >> 16);
}
__device__ __forceinline__ float sigf(float x) { return 1.f / (1.f + expf(-x)); }

// monotonic device-scope barrier: all NWG_REC WGs arrive; leader spins on agent-scope counter
__device__ __forceinline__ void gbar(uint* bar, uint target) {
    __syncthreads();
    if (threadIdx.x == 0) {
        __hip_atomic_fetch_add(bar, 1u, __ATOMIC_ACQ_REL, __HIP_MEMORY_SCOPE_AGENT);
        while (__hip_atomic_load(bar, __ATOMIC_ACQUIRE, __HIP_MEMORY_SCOPE_AGENT) < target) {
            __builtin_amdgcn_s_sleep(2);
        }
    }
    __syncthreads();
}

// ---------- k_pre: init hxA[0] hi/lo, cx; zero AH pad rows; zero barrier ----------
__global__ __launch_bounds__(256) void k_pre(ushort* hxA_hi, ushort* hxA_lo, float* cx,
                                             ushort* AH_hi, ushort* AH_lo, uint* bar,
                                             const float* h0, const float* c0) {
    int gid = blockIdx.x * 256 + threadIdx.x;
    if (gid < 32768) {
        float v = h0[gid];
        ushort hi, lo;
        splitf(v, hi, lo);
        hxA_hi[gid] = hi;
        hxA_lo[gid] = lo;
    } else if (gid < 65536) {
        cx[gid - 32768] = c0[gid - 32768];
    } else if (gid < 196608) {
        int g = gid - 65536;               // AH pad rows 1600..1663
        AH_hi[(long)Mz * 2048 + g] = 0;
        AH_lo[(long)Mz * 2048 + g] = 0;
    } else if (gid == 196608) {
        *bar = 0;
    }
}

// ---------- k_wsplit: fp32 matrix -> bf16 hi/lo planes ----------
__global__ __launch_bounds__(256) void k_wsplit(const float* __restrict__ src,
                                                ushort* __restrict__ hi, ushort* __restrict__ lo,
                                                int n4) {
    int stride = gridDim.x * 256;
    for (int i = blockIdx.x * 256 + threadIdx.x; i < n4; i += stride) {
        float4 f = *(const float4*)(src + (long)i * 4);
        float vv[4] = {f.x, f.y, f.z, f.w};
        ushort h[4], l[4];
#pragma unroll
        for (int e = 0; e < 4; ++e) splitf(vv[e], h[e], l[e]);
        uint2 hp, lp;
        hp.x = (uint)h[0] | ((uint)h[1] << 16);
        hp.y = (uint)h[2] | ((uint)h[3] << 16);
        lp.x = (uint)l[0] | ((uint)l[1] << 16);
        lp.y = (uint)l[2] | ((uint)l[3] << 16);
        *(uint2*)(hi + (long)i * 4) = hp;
        *(uint2*)(lo + (long)i * 4) = lp;
    }
}

// ---------- k_xgemm: gates_x = emb[tok] @ Wih^T + bih + bhh (split-bf16 MFMA) ----------
__global__ __launch_bounds__(256, 1) void k_xgemm(const float* __restrict__ emb,
                                                  const int* __restrict__ tok,
                                                  const float* __restrict__ Wih,
                                                  const float* __restrict__ bih,
                                                  const float* __restrict__ bhh,
                                                  float* __restrict__ gx) {
    __shared__ ushort sAh[128][40];
    __shared__ ushort sAl[128][40];
    __shared__ ushort sBh[128][40];
    __shared__ ushort sBl[128][40];
    int bid = blockIdx.x;
    int mt = bid >> 5, nt = bid & 31;
    int tid = threadIdx.x;
    int row = tid >> 1, half = tid & 1;
    int wv = tid >> 6, lane = tid & 63;
    int wr = wv >> 1, wc = wv & 1;
    int m0 = wr * 64, n0 = wc * 64;
    int r16 = lane & 15, kg = lane >> 4, k0 = kg * 8;

    f32x4 acc[4][4];
#pragma unroll
    for (int i = 0; i < 4; i++)
#pragma unroll
        for (int j = 0; j < 4; j++) acc[i][j] = (f32x4){0.f, 0.f, 0.f, 0.f};

    int r = mt * 128 + row;
    int tk = (r < Mz) ? tok[r] : 0;
    const float* arow = emb + (long)tk * Dz;
    const float* brow = Wih + (long)(nt * 128 + row) * Dz;

    for (int kb = 0; kb < Dz; kb += 32) {
        {
            ushort hh[16], ll[16];
#pragma unroll
            for (int q = 0; q < 16; q += 4) {
                float4 w4 = (r < Mz) ? *(const float4*)(arow + kb + half * 16 + q)
                                     : (float4){0.f, 0.f, 0.f, 0.f};
                float vv[4] = {w4.x, w4.y, w4.z, w4.w};
#pragma unroll
                for (int e = 0; e < 4; ++e) splitf(vv[e], hh[q + e], ll[q + e]);
            }
            *(uint4*)&sAh[row][half * 16]     = *(uint4*)&hh[0];
            *(uint4*)&sAh[row][half * 16 + 8] = *(uint4*)&hh[8];
            *(uint4*)&sAl[row][half * 16]     = *(uint4*)&ll[0];
            *(uint4*)&sAl[row][half * 16 + 8] = *(uint4*)&ll[8];
        }
        {
            ushort hh[16], ll[16];
#pragma unroll
            for (int q = 0; q < 16; q += 4) {
                float4 w4 = *(const float4*)(brow + kb + half * 16 + q);
                float vv[4] = {w4.x, w4.y, w4.z, w4.w};
#pragma unroll
                for (int e = 0; e < 4; ++e) splitf(vv[e], hh[q + e], ll[q + e]);
            }
            *(uint4*)&sBh[row][half * 16]     = *(uint4*)&hh[0];
            *(uint4*)&sBh[row][half * 16 + 8] = *(uint4*)&hh[8];
            *(uint4*)&sBl[row][half * 16]     = *(uint4*)&ll[0];
            *(uint4*)&sBl[row][half * 16 + 8] = *(uint4*)&ll[8];
        }
        __syncthreads();
        bf16x8 af[4], alf[4], bhf[4], blf[4];
#pragma unroll
        for (int i = 0; i < 4; ++i) {
            af[i]  = *(const bf16x8*)&sAh[m0 + i * 16 + r16][k0];
            alf[i] = *(const bf16x8*)&sAl[m0 + i * 16 + r16][k0];
            bhf[i] = *(const bf16x8*)&sBh[n0 + i * 16 + r16][k0];
            blf[i] = *(const bf16x8*)&sBl[n0 + i * 16 + r16][k0];
        }
#pragma unroll
        for (int i = 0; i < 4; ++i)
#pragma unroll
            for (int jn = 0; jn < 4; ++jn) {
                acc[i][jn] = __builtin_amdgcn_mfma_f32_16x16x32_bf16(af[i],  bhf[jn], acc[i][jn], 0, 0, 0);
                acc[i][jn] = __builtin_amdgcn_mfma_f32_16x16x32_bf16(af[i],  blf[jn], acc[i][jn], 0, 0, 0);
                acc[i][jn] = __builtin_amdgcn_mfma_f32_16x16x32_bf16(alf[i], bhf[jn], acc[i][jn], 0, 0, 0);
            }
        __syncthreads();
    }
#pragma unroll
    for (int i = 0; i < 4; ++i) {
        int gr0 = mt * 128 + m0 + i * 16 + kg * 4;
#pragma unroll
        for (int reg = 0; reg < 4; ++reg) {
            int gr = gr0 + reg;
            if (gr >= Mz) continue;
#pragma unroll
            for (int jn = 0; jn < 4; ++jn) {
                int gc = nt * 128 + n0 + jn * 16 + r16;
                gx[(long)gr * 4096 + gc] = acc[i][jn][reg] + bih[gc] + bhh[gc];
            }
        }
    }
}

// ---------- k_recfused2: all 50 steps, plain launch + hand-rolled agent barrier ----------
// WGs 0..63: gates MFMA + cell for step t.  WGs 64..95: attention for step t-1 (b = wid-64).
__global__ __launch_bounds__(512, 1) void k_recfused2(
    const float* __restrict__ gx,
    const ushort* __restrict__ Whi, const ushort* __restrict__ Wlo,
    ushort* __restrict__ hxA_hi, ushort* __restrict__ hxA_lo,
    float* __restrict__ hxh, float* __restrict__ cx,
    const float* __restrict__ enc,
    ushort* __restrict__ AH_hi, ushort* __restrict__ AH_lo,
    uint* bar) {
    __shared__ float sg[2][4][32][16];
    __shared__ float hxs[Hz];
    __shared__ float sc[64];
    __shared__ float aw[Sz];
    int wid = blockIdx.x, tid = threadIdx.x;

    for (int t = 0; t <= Tz; ++t) {
        if (wid < 64) {
            if (t < Tz) {
                int w = wid;
                int wave = tid >> 6, lane = tid & 63;
                int v = wave & 3, kh = wave >> 2;
                int r16 = lane & 15, kg = lane >> 4;
                int p = t & 1, q = p ^ 1;
                const ushort* Ah = hxA_hi + p * 32768;
                const ushort* Al = hxA_lo + p * 32768;
                int j = v * 1024 + w * 16 + r16;
                const ushort* bhp = Whi + (long)j * 1024;
                const ushort* blp = Wlo + (long)j * 1024;
                f32x4 acc0 = {0.f, 0.f, 0.f, 0.f}, acc1 = {0.f, 0.f, 0.f, 0.f};
                int kbase = kh * 512 + kg * 8;
#pragma unroll 4
                for (int it = 0; it < 16; ++it) {
                    int k0 = kbase + it * 32;
                    bf16x8 a_h0 = *(const bf16x8*)(Ah + r16 * 1024 + k0);
                    bf16x8 a_l0 = *(const bf16x8*)(Al + r16 * 1024 + k0);
                    bf16x8 a_h1 = *(const bf16x8*)(Ah + (16 + r16) * 1024 + k0);
                    bf16x8 a_l1 = *(const bf16x8*)(Al + (16 + r16) * 1024 + k0);
                    bf16x8 b_h = *(const bf16x8*)(bhp + k0);
                    bf16x8 b_l = *(const bf16x8*)(blp + k0);
                    acc0 = __builtin_amdgcn_mfma_f32_16x16x32_bf16(a_h0, b_h, acc0, 0, 0, 0);
                    acc0 = __builtin_amdgcn_mfma_f32_16x16x32_bf16(a_l0, b_h, acc0, 0, 0, 0);
                    acc0 = __builtin_amdgcn_mfma_f32_16x16x32_bf16(a_h0, b_l, acc0, 0, 0, 0);
                    acc1 = __builtin_amdgcn_mfma_f32_16x16x32_bf16(a_h1, b_h, acc1, 0, 0, 0);
                    acc1 = __builtin_amdgcn_mfma_f32_16x16x32_bf16(a_l1, b_h, acc1, 0, 0, 0);
                    acc1 = __builtin_amdgcn_mfma_f32_16x16x32_bf16(a_h1, b_l, acc1, 0, 0, 0);
                }
#pragma unroll
                for (int reg = 0; reg < 4; ++reg) {
                    sg[kh][v][kg * 4 + reg][r16]      = acc0[reg];
                    sg[kh][v][16 + kg * 4 + reg][r16] = acc1[reg];
                }
                __syncthreads();
                int b = tid >> 4, h16 = tid & 15;
                int hg = w * 16 + h16;
                const float* gxr = gx + ((long)b * Tz + t) * 4096 + hg;
                float gi = sg[0][0][b][h16] + sg[1][0][b][h16] + gxr[0];
                float gf = sg[0][1][b][h16] + sg[1][1][b][h16] + gxr[1024];
                float gg = sg[0][2][b][h16] + sg[1][2][b][h16] + gxr[2048];
                float go = sg[0][3][b][h16] + sg[1][3][b][h16] + gxr[3072];
                long ci = (long)b * Hz + hg;
                float c = sigf(gf) * cx[ci] + sigf(gi) * tanhf(gg);
                float hv = sigf(go) * tanhf(c);
                cx[ci] = c;
                hxh[((long)t * Bz + b) * Hz + hg] = hv;
                ushort hi, lo;
                splitf(hv, hi, lo);
                hxA_hi[q * 32768 + ci] = hi;
                hxA_lo[q * 32768 + ci] = lo;
            }
        } else {
            if (t > 0) {
                int b = wid - 64, tt = t - 1;
                const float* hsrc = hxh + ((long)tt * Bz + b) * Hz;
                *(float2*)&hxs[tid * 2] = *(const float2*)(hsrc + tid * 2);
                __syncthreads();
                int wv = tid >> 6, lane = tid & 63;
                float hreg[16];
#pragma unroll
                for (int u = 0; u < 16; ++u) hreg[u] = hxs[lane * 16 + u];
                const float* eb = enc + (long)b * Sz * Hz;
                for (int s = wv; s < Sz; s += 8) {
                    const float* er = eb + (long)s * Hz + lane * 16;
                    float sum = 0.f;
#pragma unroll
                    for (int qq = 0; qq < 4; ++qq) {
                        float4 e4 = *(const float4*)(er + qq * 4);
                        sum += e4.x * hreg[qq*4] + e4.y * hreg[qq*4+1] + e4.z * hreg[qq*4+2] + e4.w * hreg[qq*4+3];
                    }
#pragma unroll
                    for (int off = 32; off >= 1; off >>= 1) sum += __shfl_xor(sum, off);
                    if (lane == 0) sc[s] = sum;
                }
                __syncthreads();
                if (tid < 64) {
                    float vv = (tid < Sz) ? sc[tid] : -3.402823e38f;
                    float mx = vv;
#pragma unroll
                    for (int off = 32; off >= 1; off >>= 1) mx = fmaxf(mx, __shfl_xor(mx, off));
                    float e = (tid < Sz) ? expf(vv - mx) : 0.f;
                    float ssum = e;
#pragma unroll
                    for (int off = 32; off >= 1; off >>= 1) ssum += __shfl_xor(ssum, off);
                    if (tid < Sz) aw[tid] = e / ssum;
                }
                __syncthreads();
                float c0 = 0.f, c1 = 0.f;
#pragma unroll 4
                for (int s = 0; s < Sz; ++s) {
                    float2 e2 = *(const float2*)(eb + (long)s * Hz + tid * 2);
                    float a = aw[s];
                    c0 += a * e2.x; c1 += a * e2.y;
                }
                long rr = (long)b * Tz + tt;
                ushort* dh = AH_hi + rr * 2048;
                ushort* dl = AH_lo + rr * 2048;
                ushort hi, lo;
                splitf(c0, hi, lo); dh[tid * 2]        = hi; dl[tid * 2]        = lo;
                splitf(c1, hi, lo); dh[tid * 2 + 1]    = hi; dl[tid * 2 + 1]    = lo;
                splitf(hxs[tid * 2],     hi, lo); dh[1024 + tid * 2]     = hi; dl[1024 + tid * 2]     = lo;
                splitf(hxs[tid * 2 + 1], hi, lo); dh[1024 + tid * 2 + 1] = hi; dl[1024 + tid * 2 + 1] = lo;
            }
        }
        if (t < Tz) gbar(bar, (uint)NWG_REC * (uint)(t + 1));
    }
}

// ---------- k_ht: HXA = tanh(AH @ Wht^T + bht) -> bf16 hi/lo (pre-split B) ----------
__global__ __launch_bounds__(256, 1) void k_ht(const ushort* __restrict__ Ah,
                                               const ushort* __restrict__ Al,
                                               const ushort* __restrict__ Bh,
                                               const ushort* __restrict__ Bl,
                                               const float* __restrict__ bht,
                                               ushort* __restrict__ Hh, ushort* __restrict__ Hl) {
    __shared__ ushort sAh[128][40];
    __shared__ ushort sAl[128][40];
    __shared__ ushort sBh[128][40];
    __shared__ ushort sBl[128][40];
    int bid = blockIdx.x;
    int mt = bid >> 3, nt = bid & 7;
    int tid = threadIdx.x;
    int row = tid >> 1, half = tid & 1;
    int wv = tid >> 6, lane = tid & 63;
    int wr = wv >> 1, wc = wv & 1;
    int m0 = wr * 64, n0 = wc * 64;
    int r16 = lane & 15, kg = lane >> 4, k0 = kg * 8;

    f32x4 acc[4][4];
#pragma unroll
    for (int i = 0; i < 4; i++)
#pragma unroll
        for (int j = 0; j < 4; j++) acc[i][j] = (f32x4){0.f, 0.f, 0.f, 0.f};

    long arow = (long)(mt * 128 + row) * 2048;
    long brow = (long)(nt * 128 + row) * 2048;

    for (int kb = 0; kb < 2048; kb += 32) {
        const ushort* pa = Ah + arow + kb + half * 16;
        *(uint4*)&sAh[row][half * 16]     = *(const uint4*)pa;
        *(uint4*)&sAh[row][half * 16 + 8] = *(const uint4*)(pa + 8);
        const ushort* pl = Al + arow + kb + half * 16;
        *(uint4*)&sAl[row][half * 16]     = *(const uint4*)pl;
        *(uint4*)&sAl[row][half * 16 + 8] = *(const uint4*)(pl + 8);
        const ushort* pb = Bh + brow + kb + half * 16;
        *(uint4*)&sBh[row][half * 16]     = *(const uint4*)pb;
        *(uint4*)&sBh[row][half * 16 + 8] = *(const uint4*)(pb + 8);
        const ushort* pc = Bl + brow + kb + half * 16;
        *(uint4*)&sBl[row][half * 16]     = *(const uint4*)pc;
        *(uint4*)&sBl[row][half * 16 + 8] = *(const uint4*)(pc + 8);
        __syncthreads();
        bf16x8 af[4], alf[4], bhf[4], blf[4];
#pragma unroll
        for (int i = 0; i < 4; ++i) {
            af[i]  = *(const bf16x8*)&sAh[m0 + i * 16 + r16][k0];
            alf[i] = *(const bf16x8*)&sAl[m0 + i * 16 + r16][k0];
            bhf[i] = *(const bf16x8*)&sBh[n0 + i * 16 + r16][k0];
            blf[i] = *(const bf16x8*)&sBl[n0 + i * 16 + r16][k0];
        }
#pragma unroll
        for (int i = 0; i < 4; ++i)
#pragma unroll
            for (int jn = 0; jn < 4; ++jn) {
                acc[i][jn] = __builtin_amdgcn_mfma_f32_16x16x32_bf16(af[i],  bhf[jn], acc[i][jn], 0, 0, 0);
                acc[i][jn] = __builtin_amdgcn_mfma_f32_16x16x32_bf16(af[i],  blf[jn], acc[i][jn], 0, 0, 0);
                acc[i][jn] = __builtin_amdgcn_mfma_f32_16x16x32_bf16(alf[i], bhf[jn], acc[i][jn], 0, 0, 0);
            }
        __syncthreads();
    }
#pragma unroll
    for (int i = 0; i < 4; ++i) {
        int gr0 = mt * 128 + m0 + i * 16 + kg * 4;
#pragma unroll
        for (int reg = 0; reg < 4; ++reg) {
            int gr = gr0 + reg;
            bool valid = gr < Mz;
#pragma unroll
            for (int jn = 0; jn < 4; ++jn) {
                int gc = nt * 128 + n0 + jn * 16 + r16;
                float vv = tanhf(acc[i][jn][reg] + bht[gc]);
                ushort hi = 0, lo = 0;
                if (valid) splitf(vv, hi, lo);
                Hh[(long)gr * Hz + gc] = hi;
                Hl[(long)gr * Hz + gc] = lo;
            }
        }
    }
}

// ---------- k_voc3: n-panel-persistent logits GEMM (pre-split planes) + fused argmax keys ----------
__global__ __launch_bounds__(256, 1) void k_voc3(
    const ushort* __restrict__ Ah, const ushort* __restrict__ Al,
    const ushort* __restrict__ Wh, const ushort* __restrict__ Wl,
    const float* __restrict__ bvoc,
    float* __restrict__ out, ull* __restrict__ keys) {
    __shared__ ushort sAh[128][40];
    __shared__ ushort sAl[128][40];
    __shared__ ushort sBh[128][40];
    __shared__ ushort sBl[128][40];
    int bid = blockIdx.x;
    int nt = bid % 250, mg = bid / 250;       // mg in {0,1}
    int mt_beg = (mg == 0) ? 0 : 7;
    int mt_end = (mg == 0) ? 7 : 13;
    int tid = threadIdx.x;
    int row = tid >> 1, half = tid & 1;
    int wv = tid >> 6, lane = tid & 63;
    int wr = wv >> 1, wc = wv & 1;
    int m0 = wr * 64, n0 = wc * 64;
    int r16 = lane & 15, kg = lane >> 4, k0 = kg * 8;

    long wrow = (long)(nt * 128 + row) * Hz;
    int vcol_base = nt * 128 + n0;

    for (int mt = mt_beg; mt < mt_end; ++mt) {
        f32x4 acc[4][4];
#pragma unroll
        for (int i = 0; i < 4; i++)
#pragma unroll
            for (int j = 0; j < 4; j++) acc[i][j] = (f32x4){0.f, 0.f, 0.f, 0.f};

        long arow = (long)(mt * 128 + row) * Hz;

        for (int kb = 0; kb < Hz; kb += 32) {
            const ushort* pa = Ah + arow + kb + half * 16;
            *(uint4*)&sAh[row][half * 16]     = *(const uint4*)pa;
            *(uint4*)&sAh[row][half * 16 + 8] = *(const uint4*)(pa + 8);
            const ushort* pl = Al + arow + kb + half * 16;
            *(uint4*)&sAl[row][half * 16]     = *(const uint4*)pl;
            *(uint4*)&sAl[row][half * 16 + 8] = *(const uint4*)(pl + 8);
            const ushort* pb = Wh + wrow + kb + half * 16;
            *(uint4*)&sBh[row][half * 16]     = *(const uint4*)pb;
            *(uint4*)&sBh[row][half * 16 + 8] = *(const uint4*)(pb + 8);
            const ushort* pc = Wl + wrow + kb + half * 16;
            *(uint4*)&sBl[row][half * 16]     = *(const uint4*)pc;
            *(uint4*)&sBl[row][half * 16 + 8] = *(const uint4*)(pc + 8);
            __syncthreads();
            bf16x8 af[4], alf[4], bhf[4], blf[4];
#pragma unroll
            for (int i = 0; i < 4; ++i) {
                af[i]  = *(const bf16x8*)&sAh[m0 + i * 16 + r16][k0];
                alf[i] = *(const bf16x8*)&sAl[m0 + i * 16 + r16][k0];
                bhf[i] = *(const bf16x8*)&sBh[n0 + i * 16 + r16][k0];
                blf[i] = *(const bf16x8*)&sBl[n0 + i * 16 + r16][k0];
            }
#pragma unroll
            for (int i = 0; i < 4; ++i)
#pragma unroll
                for (int jn = 0; jn < 4; ++jn) {
                    acc[i][jn] = __builtin_amdgcn_mfma_f32_16x16x32_bf16(af[i],  bhf[jn], acc[i][jn], 0, 0, 0);
                    acc[i][jn] = __builtin_amdgcn_mfma_f32_16x16x32_bf16(af[i],  blf[jn], acc[i][jn], 0, 0, 0);
                    acc[i][jn] = __builtin_amdgcn_mfma_f32_16x16x32_bf16(alf[i], bhf[jn], acc[i][jn], 0, 0, 0);
                }
            __syncthreads();
        }
#pragma unroll
        for (int i = 0; i < 4; ++i) {
            int gr0 = mt * 128 + m0 + i * 16 + kg * 4;
#pragma unroll
            for (int reg = 0; reg < 4; ++reg) {
                int gr = gr0 + reg;
                bool valid = gr < Mz;
                float bestv = -3.402823e38f;
                int bestc = 0;
#pragma unroll
                for (int jn = 0; jn < 4; ++jn) {
                    int gc = vcol_base + jn * 16 + r16;
                    float v = acc[i][jn][reg] + bvoc[gc];
                    if (valid) __builtin_nontemporal_store(v, &out[(long)gr * Vz + gc]);
                    if (v > bestv) { bestv = v; bestc = gc; }
                }
#pragma unroll
                for (int off = 1; off < 16; off <<= 1) {
                    float ov = __shfl_xor(bestv, off);
                    int oc = __shfl_xor(bestc, off);
                    if (ov > bestv || (ov == bestv && oc < bestc)) { bestv = ov; bestc = oc; }
                }
                if (valid && r16 == 0) {
                    uint u = __builtin_bit_cast(uint, bestv);
                    u = (u & 0x80000000u) ? ~u : (u | 0x80000000u);
                    keys[(long)gr * 512 + nt * 2 + wc] = (((ull)u) << 32) | (ull)(65535 - bestc);
                }
            }
        }
    }
}

__global__ __launch_bounds__(256) void k_argmax2(const ull* __restrict__ keys, float* __restrict__ pred) {
    int r = blockIdx.x, tid = threadIdx.x;
    ull best = 0;
    for (int j = tid; j < 500; j += 256) {
        ull k = keys[(long)r * 512 + j];
        if (k > best) best = k;
    }
    __shared__ ull sk[256];
    sk[tid] = best;
    __syncthreads();
    for (int s = 128; s > 0; s >>= 1) {
        if (tid < s) { if (sk[tid + s] > sk[tid]) sk[tid] = sk[tid + s]; }
        __syncthreads();
    }
    if (tid == 0) pred[r] = (float)(65535 - (int)(sk[0] & 0xFFFFull));
}

// ---------------- host ----------------
extern "C" void kernel_launch(void* const* d_in, const int* in_sizes, int n_in,
                              void* d_out, int out_size, void* d_ws, size_t ws_size,
                              hipStream_t stream) {
    const int*   tok  = (const int*)d_in[0];
    const float* enc  = (const float*)d_in[1];
    const float* h0   = (const float*)d_in[2];
    const float* c0   = (const float*)d_in[3];
    const float* emb  = (const float*)d_in[6];
    const float* Wih  = (const float*)d_in[7];
    const float* Whh  = (const float*)d_in[8];
    const float* bih  = (const float*)d_in[9];
    const float* bhh  = (const float*)d_in[10];
    const float* Wht  = (const float*)d_in[11];
    const float* bht  = (const float*)d_in[12];
    const float* Wvoc = (const float*)d_in[13];
    const float* bvoc = (const float*)d_in[14];
    float* out = (float*)d_out;

    char* base = (char*)d_ws;
    // --- recurrence-phase region [0, 131MB): dead before k_voc3; overwritten by Wvoc planes ---
    size_t off = 0;
    float*  gx      = (float*)(base + off);  off += (size_t)Mz * 4096 * 4;       // 26.2 MB
    ushort* hxA_hi  = (ushort*)(base + off); off += 2 * 32768 * 2;
    ushort* hxA_lo  = (ushort*)(base + off); off += 2 * 32768 * 2;
    float*  cx      = (float*)(base + off);  off += 32768 * 4;
    float*  hxh     = (float*)(base + off);  off += (size_t)Tz * Bz * Hz * 4;    // 6.55 MB
    ushort* AH_hi   = (ushort*)(base + off); off += (size_t)Mp * 2048 * 2;       // 6.8 MB
    ushort* AH_lo   = (ushort*)(base + off); off += (size_t)Mp * 2048 * 2;
    ushort* Whh_hi  = (ushort*)(base + off); off += (size_t)4096 * 1024 * 2;
    ushort* Whh_lo  = (ushort*)(base + off); off += (size_t)4096 * 1024 * 2;
    ushort* Wht_hi  = (ushort*)(base + off); off += (size_t)1024 * 2048 * 2;
    ushort* Wht_lo  = (ushort*)(base + off); off += (size_t)1024 * 2048 * 2;     // ~72 MB total
    // aliased Wvoc planes (written after k_ht, when the region above is dead)
    ushort* Wvoc_hi = (ushort*)base;                                             // 65.5 MB
    ushort* Wvoc_lo = Wvoc_hi + (size_t)Vz * Hz;                                 // 65.5 MB (ends 131 MB)
    // --- survivors past 131 MB ---
    size_t off2 = (size_t)Vz * Hz * 2 * 2;                                       // 131,072,000
    ushort* HXA_hi  = (ushort*)(base + off2); off2 += (size_t)Mp * 1024 * 2;
    ushort* HXA_lo  = (ushort*)(base + off2); off2 += (size_t)Mp * 1024 * 2;
    ull*    keys    = (ull*)(base + off2);    off2 += (size_t)Mz * 512 * 8;      // ends ~144.4 MB
    uint*   bar     = (uint*)(base + off2);   off2 += 256;

    k_pre<<<769, 256, 0, stream>>>(hxA_hi, hxA_lo, cx, AH_hi, AH_lo, bar, h0, c0);
    k_wsplit<<<1024, 256, 0, stream>>>(Whh, Whh_hi, Whh_lo, 4096 * 1024 / 4);
    k_wsplit<<<512, 256, 0, stream>>>(Wht, Wht_hi, Wht_lo, 1024 * 2048 / 4);
    k_xgemm<<<13 * 32, 256, 0, stream>>>(emb, tok, Wih, bih, bhh, gx);

    k_recfused2<<<NWG_REC, 512, 0, stream>>>(gx, Whh_hi, Whh_lo, hxA_hi, hxA_lo, hxh, cx,
                                             enc, AH_hi, AH_lo, bar);

    k_ht<<<13 * 8, 256, 0, stream>>>(AH_hi, AH_lo, Wht_hi, Wht_lo, bht, HXA_hi, HXA_lo);
    k_wsplit<<<2048, 256, 0, stream>>>(Wvoc, Wvoc_hi, Wvoc_lo, Vz * Hz / 4);
    k_voc3<<<500, 256, 0, stream>>>(HXA_hi, HXA_lo, Wvoc_hi, Wvoc_lo, bvoc, out, keys);
    k_argmax2<<<Mz, 256, 0, stream>>>(keys, out + (long)Mz * Vz);
}